// Round 3
// baseline (1441.611 us; speedup 1.0000x reference)
//
#include <hip/hip_runtime.h>
#include <hip/hip_bf16.h>

typedef __attribute__((ext_vector_type(8))) short bf16x8;
typedef __attribute__((ext_vector_type(4))) float f32x4;

#define L_SZ 1024
#define D_SZ 64
#define SCALE 0.125f

__device__ __forceinline__ short f2bf(float f) {
    union { float f; unsigned u; } v; v.f = f;
    unsigned r = (v.u + 0x7fffu + ((v.u >> 16) & 1u)) >> 16;  // RNE
    return (short)r;
}

__device__ __forceinline__ bf16x8 cvt8(const float* __restrict__ p) {
    f32x4 a = *(const f32x4*)p;
    f32x4 b = *(const f32x4*)(p + 4);
    bf16x8 r;
    r[0] = f2bf(a[0]); r[1] = f2bf(a[1]); r[2] = f2bf(a[2]); r[3] = f2bf(a[3]);
    r[4] = f2bf(b[0]); r[5] = f2bf(b[1]); r[6] = f2bf(b[2]); r[7] = f2bf(b[3]);
    return r;
}

#define MFMA(A, Bf, C) __builtin_amdgcn_mfma_f32_16x16x32_bf16(A, Bf, C, 0, 0, 0)

// ---------------------------------------------------------------------------
// Pre-pass: src [outer][1024][64] f32 -> dst [outer][64][1024] bf16.
// f32 [64][65] LDS tile (padded -> ~2-way banks on both sides), cvt on read.
// ---------------------------------------------------------------------------
__global__ void tr64_bf16_k(const float* __restrict__ src, short* __restrict__ dst) {
    __shared__ float tile[64 * 65];
    const int kt = blockIdx.x;
    const size_t o = blockIdx.y;
    const int tid = threadIdx.x;
    {
        const int rr = tid >> 2, c0 = (tid & 3) << 4;
        const float* sp = src + (o * L_SZ + (size_t)(kt * 64 + rr)) * D_SZ + c0;
        f32x4 v0 = *(const f32x4*)sp;
        f32x4 v1 = *(const f32x4*)(sp + 4);
        f32x4 v2 = *(const f32x4*)(sp + 8);
        f32x4 v3 = *(const f32x4*)(sp + 12);
        float* tp = tile + rr * 65 + c0;
        tp[0] = v0[0];  tp[1] = v0[1];  tp[2] = v0[2];  tp[3] = v0[3];
        tp[4] = v1[0];  tp[5] = v1[1];  tp[6] = v1[2];  tp[7] = v1[3];
        tp[8] = v2[0];  tp[9] = v2[1];  tp[10] = v2[2]; tp[11] = v2[3];
        tp[12] = v3[0]; tp[13] = v3[1]; tp[14] = v3[2]; tp[15] = v3[3];
    }
    __syncthreads();
    {
        const int d = tid >> 2, k4 = (tid & 3) << 4;
        bf16x8 o0, o1;
#pragma unroll
        for (int j = 0; j < 8; ++j) {
            o0[j] = f2bf(tile[(k4 + j) * 65 + d]);
            o1[j] = f2bf(tile[(k4 + 8 + j) * 65 + d]);
        }
        short* dp = dst + (o * 64 + (size_t)d) * L_SZ + kt * 64 + k4;
        *(bf16x8*)dp       = o0;
        *(bf16x8*)(dp + 8) = o1;
    }
}

// ---------------------------------------------------------------------------
// Main kernel: block = 256 threads (4 waves), tile = 16 batches x 16 queries x
// 512 keys (k-split across grid). Grid = 512 blocks -> 2 independent blocks
// per CU (desynchronized barrier streams). 2 barriers per k-iteration.
// Q/K/PK read as f32 (cvt in-kernel, stall-hidden); V/PV from transposed bf16.
// Partial (unnormalized O, l) written to workspace; merged by merge_k.
// ---------------------------------------------------------------------------
__global__ __launch_bounds__(256, 2) void rpr_attn2(
    const float* __restrict__ Q, const float* __restrict__ K,
    const float* __restrict__ PK,
    const short* __restrict__ Vt, const short* __restrict__ PVt,
    const int* __restrict__ VLEN,
    float* __restrict__ Opart, float* __restrict__ Lp)
{
    // SH: [0,8192) f32 = SA score exchange (32 KB); [8192,16384) = PB bf16 P
    // (32 KB); [16384,16640) = lbuf. Epilogue overlays Obuf on SH[0,16384).
    __shared__ __attribute__((aligned(16))) float SH[16384 + 256];
    char* sa = (char*)&SH[0];
    char* pb = (char*)&SH[8192];
    float* lbuf = &SH[16384];

    const int tid = threadIdx.x;
    const int r = tid >> 6, lane = tid & 63;
    const int lane15 = lane & 15, quad = lane >> 4;

    // XCD-aware swizzle (512 % 8 == 0 -> bijective): each XCD gets 8 q-tiles
    // x 4 b-tiles x 2 k-splits, so blocks sharing pos tables co-reside.
    const int n = blockIdx.x;
    const int l = (n & 7) * 64 + (n >> 3);
    const int b0 = (l & 3) * 16;          // batch tile
    const int ks = (l >> 2) & 1;          // k-split half
    const int q0 = (l >> 3) * 16;         // query tile

    // ---- Q fragments (f32 -> bf16 once) ----
    bf16x8 qa[4][2], qp[4][2];
    int vl[4];
#pragma unroll
    for (int j = 0; j < 4; ++j) {
        const int bl = r * 4 + j;
        vl[j] = VLEN[b0 + bl];
        const float* pc = Q + ((b0 + bl) * L_SZ + q0 + lane15) * D_SZ + quad * 8;
        qa[j][0] = cvt8(pc); qa[j][1] = cvt8(pc + 32);
        const float* pp = Q + ((b0 + lane15) * L_SZ + q0 + bl) * D_SZ + quad * 8;
        qp[j][0] = cvt8(pp); qp[j][1] = cvt8(pp + 32);
    }

    f32x4 Oc[4][4], Op[4][4];   // content O[b][q x d], pos O[q][b x d]
    float es[4][4];
#pragma unroll
    for (int j = 0; j < 4; ++j)
#pragma unroll
        for (int nt = 0; nt < 4; ++nt) {
            Oc[j][nt] = (f32x4){0.f, 0.f, 0.f, 0.f};
            Op[j][nt] = (f32x4){0.f, 0.f, 0.f, 0.f};
            es[j][nt] = 0.f;
        }

    for (int it = 0; it < 16; ++it) {
        const int kb = ks * 512 + it * 32;

        // ---- phase 1: pos scores S_p[q](b x k) -> SA (f32, swizzled) ----
#pragma unroll
        for (int j = 0; j < 4; ++j) {
            const int ql = r * 4 + j;
#pragma unroll
            for (int c = 0; c < 2; ++c) {
                const float* bp = PK + ((q0 + ql) * L_SZ + kb + c * 16 + lane15) * D_SZ + quad * 8;
                f32x4 acc = (f32x4){0.f, 0.f, 0.f, 0.f};
                acc = MFMA(qp[j][0], cvt8(bp), acc);
                acc = MFMA(qp[j][1], cvt8(bp + 32), acc);
#pragma unroll
                for (int i = 0; i < 4; ++i) {
                    const int brow = quad * 4 + i;
                    const int off = (((brow * 16 + ql) * 32 + c * 16 + lane15) * 4)
                                    ^ (((brow ^ ql) & 7) << 4);
                    *(float*)(sa + off) = acc[i];
                }
            }
        }
        __syncthreads();

        // ---- phase 2: content scores + combine + mask + exp -> PB (bf16) ----
#pragma unroll
        for (int j = 0; j < 4; ++j) {
            const int bl = r * 4 + j;
#pragma unroll
            for (int c = 0; c < 2; ++c) {
                const float* bp = K + ((b0 + bl) * L_SZ + kb + c * 16 + lane15) * D_SZ + quad * 8;
                f32x4 acc = (f32x4){0.f, 0.f, 0.f, 0.f};
                acc = MFMA(qa[j][0], cvt8(bp), acc);
                acc = MFMA(qa[j][1], cvt8(bp + 32), acc);
                const int kg = kb + c * 16 + lane15;
#pragma unroll
                for (int i = 0; i < 4; ++i) {
                    const int q = quad * 4 + i;
                    const int soff = (((bl * 16 + q) * 32 + c * 16 + lane15) * 4)
                                     ^ (((bl ^ q) & 7) << 4);
                    const float s = (acc[i] + *(const float*)(sa + soff)) * SCALE;
                    float e;
                    if (vl[j] == 0)       e = 1.0f;          // fully-masked row -> uniform attn
                    else if (kg < vl[j])  e = __expf(s);
                    else                  e = 0.0f;
                    es[j][i] += e;
                    const int poff = (((bl * 16 + q) * 64 + c * 16 + lane15) * 2)
                                     ^ (((bl ^ q) & 7) << 4);
                    *(short*)(pb + poff) = f2bf(e);
                }
            }
        }
        __syncthreads();

        // ---- phase 3: PV contractions (reads PB + Vt/PVt only; no barrier
        // after -- next phase 1 writes SA which is ordered by the barriers
        // above, so phase 3 fuses with the next iteration's PK loads) ----
        __builtin_amdgcn_s_setprio(1);
#pragma unroll
        for (int j = 0; j < 4; ++j) {
            const int bl = r * 4 + j;
            const int aoff = (((bl * 16 + lane15) * 64) * 2 + quad * 16)
                             ^ (((bl ^ lane15) & 7) << 4);
            const bf16x8 af = *(const bf16x8*)(pb + aoff);
            const short* vb = Vt + ((b0 + bl) * 64 + lane15) * L_SZ + kb + quad * 8;
#pragma unroll
            for (int nt = 0; nt < 4; ++nt) {
                const bf16x8 bf = *(const bf16x8*)(vb + nt * 16 * L_SZ);
                Oc[j][nt] = MFMA(af, bf, Oc[j][nt]);
            }
        }
#pragma unroll
        for (int j = 0; j < 4; ++j) {
            const int ql = r * 4 + j;
            const int aoff = (((lane15 * 16 + ql) * 64) * 2 + quad * 16)
                             ^ (((lane15 ^ ql) & 7) << 4);
            const bf16x8 af = *(const bf16x8*)(pb + aoff);
            const short* vb = PVt + ((q0 + ql) * 64 + lane15) * L_SZ + kb + quad * 8;
#pragma unroll
            for (int nt = 0; nt < 4; ++nt) {
                const bf16x8 bf = *(const bf16x8*)(vb + nt * 16 * L_SZ);
                Op[j][nt] = MFMA(af, bf, Op[j][nt]);
            }
        }
        __builtin_amdgcn_s_setprio(0);
    }

    // ---- l reduction over the 16 k-columns (lane15) -> lbuf ----
#pragma unroll
    for (int j = 0; j < 4; ++j)
#pragma unroll
        for (int i = 0; i < 4; ++i) {
            float s = es[j][i];
            s += __shfl_xor(s, 1);
            s += __shfl_xor(s, 2);
            s += __shfl_xor(s, 4);
            s += __shfl_xor(s, 8);
            if (lane15 == 0)
                lbuf[(r * 4 + j) * 16 + quad * 4 + i] = s;
        }
    __syncthreads();   // all phase-3 PB reads + lbuf writes complete

    // ---- epilogue: merge Oc/Op across waves via Obuf overlay ----
    float* Obuf = &SH[0];   // 16384 f32 (overlays SA+PB)

#pragma unroll
    for (int j = 0; j < 4; ++j)
#pragma unroll
        for (int nt = 0; nt < 4; ++nt)
#pragma unroll
            for (int i = 0; i < 4; ++i)
                Obuf[((r * 4 + j) * 16 + quad * 4 + i) * 64 + nt * 16 + lane15] = Oc[j][nt][i];
    __syncthreads();
#pragma unroll
    for (int j = 0; j < 4; ++j)
#pragma unroll
        for (int nt = 0; nt < 4; ++nt)
#pragma unroll
            for (int i = 0; i < 4; ++i)
                Obuf[((quad * 4 + i) * 16 + r * 4 + j) * 64 + nt * 16 + lane15] += Op[j][nt][i];
    __syncthreads();

    // ---- write partial O (unnormalized) + l to workspace ----
    const size_t obase = (size_t)ks * 4194304;   // 64*1024*64 floats per split
    for (int idx = tid; idx < 4096; idx += 256) {
        const int d4 = idx & 15, ql2 = (idx >> 4) & 15, bl2 = idx >> 8;
        f32x4 o = *(const f32x4*)&Obuf[(bl2 * 16 + ql2) * 64 + d4 * 4];
        *(f32x4*)&Opart[obase + (((size_t)(b0 + bl2) * L_SZ) + q0 + ql2) * D_SZ + d4 * 4] = o;
    }
    {
        const int ql2 = tid & 15, bl2 = tid >> 4;
        Lp[ks * 65536 + (b0 + bl2) * L_SZ + q0 + ql2] = lbuf[bl2 * 16 + ql2];
    }
}

// ---------------------------------------------------------------------------
// Merge: OUT = (O0 + O1) / (l0 + l1).
// ---------------------------------------------------------------------------
__global__ void merge_k(const float* __restrict__ Opart, const float* __restrict__ Lp,
                        float* __restrict__ OUT) {
    const int stride = gridDim.x * blockDim.x;
    for (int u = blockIdx.x * blockDim.x + threadIdx.x; u < 1048576; u += stride) {
        const int bq = u >> 4;
        const float rl = 1.0f / (Lp[bq] + Lp[65536 + bq]);
        f32x4 a = *(const f32x4*)(Opart + (size_t)u * 4);
        f32x4 b = *(const f32x4*)(Opart + 4194304ull + (size_t)u * 4);
        f32x4 o;
        o[0] = (a[0] + b[0]) * rl;
        o[1] = (a[1] + b[1]) * rl;
        o[2] = (a[2] + b[2]) * rl;
        o[3] = (a[3] + b[3]) * rl;
        *(f32x4*)(OUT + (size_t)u * 4) = o;
    }
}

// ---------------------------------------------------------------------------
// Fallback kernel (round-0 verified best) — used only if ws_size too small.
// ---------------------------------------------------------------------------
#define KP 36          // k pitch (floats)
#define BPITCH 580     // 16*KP + 4
#define SA_SZ 9280     // 16*BPITCH floats per k-group

__global__ __launch_bounds__(512, 2) void rpr_attn(
    const float* __restrict__ Q, const float* __restrict__ Kt,
    const float* __restrict__ V, const float* __restrict__ PK,
    const float* __restrict__ PV, const int* __restrict__ VLEN,
    float* __restrict__ OUT)
{
    __shared__ float SA[2][SA_SZ];
    __shared__ float lbuf[2][256];

    const int tid = threadIdx.x;
    const int wave = tid >> 6, lane = tid & 63;
    const int g = wave >> 2, r = wave & 3;
    const int lane15 = lane & 15, quad = lane >> 4;
    const int b0 = blockIdx.x * 16;
    const int q0 = blockIdx.y * 16;

    float* sa = SA[g];

    bf16x8 qa[4][2], qp[4][2];
    int vl[4];
#pragma unroll
    for (int j = 0; j < 4; ++j) {
        const int bl = r * 4 + j;
        vl[j] = VLEN[b0 + bl];
        const float* pc = Q + ((b0 + bl) * L_SZ + q0 + lane15) * D_SZ + quad * 8;
        qa[j][0] = cvt8(pc); qa[j][1] = cvt8(pc + 32);
        const float* pp = Q + ((b0 + lane15) * L_SZ + q0 + bl) * D_SZ + quad * 8;
        qp[j][0] = cvt8(pp); qp[j][1] = cvt8(pp + 32);
    }

    f32x4 Oc[4][4], Op[4][4];
#pragma unroll
    for (int j = 0; j < 4; ++j)
#pragma unroll
        for (int nt = 0; nt < 4; ++nt) {
            Oc[j][nt] = (f32x4){0.f, 0.f, 0.f, 0.f};
            Op[j][nt] = (f32x4){0.f, 0.f, 0.f, 0.f};
        }
    float l_acc = 0.f;

    const int tg = r * 64 + lane;
    const int lb = tg >> 4, lq = tg & 15;

    for (int it = 0; it < 16; ++it) {
        const int kb = g * 512 + it * 32;

#pragma unroll
        for (int j = 0; j < 4; ++j) {
            const int ql = r * 4 + j;
#pragma unroll
            for (int c = 0; c < 2; ++c) {
                const float* bp = PK + ((q0 + ql) * L_SZ + kb + c * 16 + lane15) * D_SZ + quad * 8;
                f32x4 acc = (f32x4){0.f, 0.f, 0.f, 0.f};
                acc = MFMA(qp[j][0], cvt8(bp), acc);
                acc = MFMA(qp[j][1], cvt8(bp + 32), acc);
#pragma unroll
                for (int i = 0; i < 4; ++i)
                    sa[(quad * 4 + i) * BPITCH + ql * KP + c * 16 + lane15] = acc[i];
            }
        }
        __syncthreads();

#pragma unroll
        for (int j = 0; j < 4; ++j) {
            const int bl = r * 4 + j;
#pragma unroll
            for (int c = 0; c < 2; ++c) {
                const float* bp = Kt + ((b0 + bl) * L_SZ + kb + c * 16 + lane15) * D_SZ + quad * 8;
                f32x4 acc = (f32x4){0.f, 0.f, 0.f, 0.f};
                acc = MFMA(qa[j][0], cvt8(bp), acc);
                acc = MFMA(qa[j][1], cvt8(bp + 32), acc);
                const int kg = kb + c * 16 + lane15;
#pragma unroll
                for (int i = 0; i < 4; ++i) {
                    const int idx = bl * BPITCH + (quad * 4 + i) * KP + c * 16 + lane15;
                    const float s = (acc[i] + sa[idx]) * SCALE;
                    float e;
                    if (vl[j] == 0)       e = 1.0f;
                    else if (kg < vl[j])  e = __expf(s);
                    else                  e = 0.0f;
                    sa[idx] = e;
                }
            }
        }
        __syncthreads();

        {
            const float* row = sa + lb * BPITCH + lq * KP;
            float s = 0.f;
#pragma unroll
            for (int kk = 0; kk < 32; kk += 4) {
                f32x4 v4 = *(const f32x4*)(row + kk);
                s += v4[0] + v4[1] + v4[2] + v4[3];
            }
            l_acc += s;
        }
#pragma unroll
        for (int j = 0; j < 4; ++j) {
            const int bl = r * 4 + j;
            const bf16x8 af = cvt8(sa + bl * BPITCH + lane15 * KP + quad * 8);
            const float* vb = V + ((b0 + bl) * L_SZ + kb + quad * 8) * D_SZ + lane15;
#pragma unroll
            for (int nt = 0; nt < 4; ++nt) {
                bf16x8 bf;
#pragma unroll
                for (int jj = 0; jj < 8; ++jj) bf[jj] = f2bf(vb[jj * D_SZ + nt * 16]);
                Oc[j][nt] = MFMA(af, bf, Oc[j][nt]);
            }
        }
#pragma unroll
        for (int j = 0; j < 4; ++j) {
            const int ql = r * 4 + j;
            const bf16x8 af = cvt8(sa + lane15 * BPITCH + ql * KP + quad * 8);
            const float* vb = PV + ((q0 + ql) * L_SZ + kb + quad * 8) * D_SZ + lane15;
#pragma unroll
            for (int nt = 0; nt < 4; ++nt) {
                bf16x8 bf;
#pragma unroll
                for (int jj = 0; jj < 8; ++jj) bf[jj] = f2bf(vb[jj * D_SZ + nt * 16]);
                Op[j][nt] = MFMA(af, bf, Op[j][nt]);
            }
        }
        __syncthreads();
    }

    lbuf[g][tg] = l_acc;
    float* Obuf = &SA[0][0];

    if (g == 0) {
#pragma unroll
        for (int j = 0; j < 4; ++j)
#pragma unroll
            for (int nt = 0; nt < 4; ++nt)
#pragma unroll
                for (int i = 0; i < 4; ++i)
                    Obuf[((r * 4 + j) * 16 + quad * 4 + i) * 64 + nt * 16 + lane15] = Oc[j][nt][i];
    }
    __syncthreads();
    if (g == 1) {
#pragma unroll
        for (int j = 0; j < 4; ++j)
#pragma unroll
            for (int nt = 0; nt < 4; ++nt)
#pragma unroll
                for (int i = 0; i < 4; ++i)
                    Obuf[((r * 4 + j) * 16 + quad * 4 + i) * 64 + nt * 16 + lane15] += Oc[j][nt][i];
    }
    __syncthreads();
    if (g == 0) {
#pragma unroll
        for (int j = 0; j < 4; ++j)
#pragma unroll
            for (int nt = 0; nt < 4; ++nt)
#pragma unroll
                for (int i = 0; i < 4; ++i)
                    Obuf[((quad * 4 + i) * 16 + r * 4 + j) * 64 + nt * 16 + lane15] += Op[j][nt][i];
    }
    __syncthreads();
    if (g == 1) {
#pragma unroll
        for (int j = 0; j < 4; ++j)
#pragma unroll
            for (int nt = 0; nt < 4; ++nt)
#pragma unroll
                for (int i = 0; i < 4; ++i)
                    Obuf[((quad * 4 + i) * 16 + r * 4 + j) * 64 + nt * 16 + lane15] += Op[j][nt][i];
    }
    __syncthreads();

    for (int idx = tid; idx < 4096; idx += 512) {
        const int d4 = idx & 15, ql2 = (idx >> 4) & 15, bl2 = idx >> 8;
        const float li = lbuf[0][bl2 * 16 + ql2] + lbuf[1][bl2 * 16 + ql2];
        const float rl = 1.0f / li;
        f32x4 o = *(const f32x4*)&Obuf[(bl2 * 16 + ql2) * 64 + d4 * 4];
        o[0] *= rl; o[1] *= rl; o[2] *= rl; o[3] *= rl;
        *(f32x4*)&OUT[((b0 + bl2) * L_SZ + q0 + ql2) * D_SZ + d4 * 4] = o;
    }
}

extern "C" void kernel_launch(void* const* d_in, const int* in_sizes, int n_in,
                              void* d_out, int out_size, void* d_ws, size_t ws_size,
                              hipStream_t stream) {
    (void)in_sizes; (void)n_in; (void)out_size;
    const float* Q  = (const float*)d_in[0];
    const float* K  = (const float*)d_in[1];
    const float* V  = (const float*)d_in[2];
    const float* PK = (const float*)d_in[3];
    const float* PV = (const float*)d_in[4];
    const int*   VL = (const int*)d_in[5];
    float* OUT = (float*)d_out;

    // Workspace layout:
    //   Vt    [64][64][1024]  bf16   8,388,608 B
    //   PVt   [1024][64][1024] bf16  134,217,728 B
    //   Opart [2][64][1024][64] f32  33,554,432 B
    //   Lp    [2][64][1024]    f32   524,288 B
    const size_t WS_NEEDED = 8388608ull + 134217728ull + 33554432ull + 524288ull; // 176,685,056

    if (d_ws != nullptr && ws_size >= WS_NEEDED) {
        short* Vt    = (short*)d_ws;
        short* PVt   = Vt + 4194304;
        float* Opart = (float*)(PVt + 67108864);
        float* Lp    = Opart + 8388608;

        tr64_bf16_k<<<dim3(16, 64),   dim3(256), 0, stream>>>(V, Vt);
        tr64_bf16_k<<<dim3(16, 1024), dim3(256), 0, stream>>>(PV, PVt);
        rpr_attn2<<<dim3(512), dim3(256), 0, stream>>>(Q, K, PK, Vt, PVt, VL, Opart, Lp);
        merge_k<<<dim3(2048), dim3(256), 0, stream>>>(Opart, Lp, OUT);
    } else {
        dim3 grid(4, 64, 1);
        dim3 block(512, 1, 1);
        rpr_attn<<<grid, block, 0, stream>>>(Q, K, V, PK, PV, VL, OUT);
    }
}